// Round 1
// 660.644 us; speedup vs baseline: 1.1426x; 1.1426x over previous
//
#include <hip/hip_runtime.h>
#include <hip/hip_bf16.h>
#include <stdint.h>

// Problem constants (from reference): DEPTH=4, B=4096, H=E=1024
#define DEPTH 4
#define Bb 4096
#define Hh 1024
#define Ee 1024
#define Kd 2048   // E + H
#define Ng 4096   // 4*H
#define NT (Kd / 64)  // 32 K-tiles of BK=64

typedef __attribute__((ext_vector_type(8))) short short8;   // 8 bf16 = 4 VGPRs
typedef __attribute__((ext_vector_type(4))) float floatx4;  // MFMA C/D frag
typedef __attribute__((ext_vector_type(4))) float f32x4;

__device__ __forceinline__ float fast_sigmoid(float x) {
  return 1.0f / (1.0f + __expf(-x));
}
__device__ __forceinline__ float fast_tanh(float x) {
  float t = __expf(-2.0f * fabsf(x));
  return copysignf((1.0f - t) / (1.0f + t), x);
}

// async global->LDS, 16B per lane; LDS dest = wave-uniform base + lane*16
__device__ __forceinline__ void gload_lds16(const void* g, void* l) {
  __builtin_amdgcn_global_load_lds(
      (const __attribute__((address_space(1))) void*)(uintptr_t)g,
      (__attribute__((address_space(3))) void*)(uint32_t)(uintptr_t)l,
      16, 0, 0);
}

// ---------------------------------------------------------------------------
// W[l][k][n] (f32) -> Wt[l][n][k] (bf16). Tile 128(k) x 64(n), block 256.
// (unchanged from previous round; candidate for next round once counters show)
// ---------------------------------------------------------------------------
__global__ __launch_bounds__(256) void transpose_w_kernel(
    const float* __restrict__ W, __hip_bfloat16* __restrict__ Wt) {
  __shared__ __attribute__((aligned(16))) float ldsT[64 * 132];  // 33 KB
  const int l = blockIdx.z;
  const int k0 = blockIdx.x * 128;
  const int n0 = blockIdx.y * 64;
  const float* Wl = W + (size_t)l * Kd * Ng + (size_t)k0 * Ng + n0;
  __hip_bfloat16* Wtl = Wt + (size_t)l * Ng * Kd;
  const int tid = threadIdx.x;

#pragma unroll
  for (int i = 0; i < 8; i++) {
    const int flat = tid + 256 * i;
    const int k = flat >> 4;            // 0..127
    const int c4 = (flat & 15) * 4;     // n offset 0..60
    const f32x4 v = *(const f32x4*)(Wl + (size_t)k * Ng + c4);
    const int grp = k >> 3;             // 8-f32 (32B) group along k
    const int klo = k & 7;
#pragma unroll
    for (int j = 0; j < 4; j++) {
      const int n = c4 + j;
      ldsT[n * 132 + ((grp ^ ((n >> 2) & 3)) << 3) + klo] = v[j];
    }
  }
  __syncthreads();

#pragma unroll
  for (int i = 0; i < 4; i++) {
    const int c = tid + 256 * i;
    const int n = c >> 4;     // 0..63
    const int kc = c & 15;    // 16B output chunk = 8 k
    const int g = kc ^ ((n >> 2) & 3);
    const float* src = &ldsT[n * 132 + (g << 3)];
    const f32x4 u0 = *(const f32x4*)src;
    const f32x4 u1 = *(const f32x4*)(src + 4);
    union {
      __hip_bfloat16 h[8];
      short8 s;
    } p;
    p.h[0] = __float2bfloat16(u0.x);
    p.h[1] = __float2bfloat16(u0.y);
    p.h[2] = __float2bfloat16(u0.z);
    p.h[3] = __float2bfloat16(u0.w);
    p.h[4] = __float2bfloat16(u1.x);
    p.h[5] = __float2bfloat16(u1.y);
    p.h[6] = __float2bfloat16(u1.z);
    p.h[7] = __float2bfloat16(u1.w);
    *(short8*)&Wtl[(size_t)(n0 + n) * Kd + k0 + kc * 8] = p.s;
  }
}

// ---------------------------------------------------------------------------
// xh[l] = [bf16(layer_input) | bf16(s_h[l])], layout [DEPTH][Bb][Kd] bf16.
// ---------------------------------------------------------------------------
__global__ __launch_bounds__(256) void prefill_xh_kernel(
    const float* __restrict__ x, const float* __restrict__ s_h,
    __hip_bfloat16* __restrict__ xh) {
  const int idx = blockIdx.x * blockDim.x + threadIdx.x;  // float4 index
  const int XN = Bb * Ee / 4;                             // 2^20
  const int TOTAL = XN + DEPTH * Bb * Hh / 4;
  if (idx >= TOTAL) return;
  const float* srcp;
  __hip_bfloat16* dst;
  if (idx < XN) {
    const int b = idx >> 8;  // Ee/4 = 256
    const int j4 = idx & 255;
    srcp = x + (size_t)idx * 4;
    dst = xh + (size_t)b * Kd + j4 * 4;
  } else {
    const int e4 = idx - XN;
    const int l = e4 >> 20;  // Bb*Hh/4 = 2^20
    const int r = e4 & 0xFFFFF;
    const int b = r >> 8;  // Hh/4 = 256
    const int j4 = r & 255;
    srcp = s_h + (size_t)e4 * 4;
    dst = xh + (size_t)l * Bb * Kd + (size_t)b * Kd + Ee + j4 * 4;
  }
  f32x4 v = *(const f32x4*)srcp;
  union {
    __hip_bfloat16 h[4];
    unsigned long long u;
  } p;
  p.h[0] = __float2bfloat16(v.x);
  p.h[1] = __float2bfloat16(v.y);
  p.h[2] = __float2bfloat16(v.z);
  p.h[3] = __float2bfloat16(v.w);
  *(unsigned long long*)dst = p.u;
}

// ---------------------------------------------------------------------------
// Fused GEMM + LSTM cell, 256^2 8-phase schedule (T2+T3+T4+T5).
// A = xh[l] [Bb][Kd] bf16;  Wt [Ng][Kd] bf16 (row n = gate*1024 + j)
// Block: 256 rows x (4 gates x 64 j); 512 thr = 8 waves (2M x 4N);
// wave output 128x64; N-frag index == gate -> pure per-lane epilogue.
// LDS 128 KiB = dbuf x {A 256x64, B 256x64} bf16. Swizzle: source chunk
// q = p ^ (row&7) staged at phys slot p (linear gload_lds dest), reads XOR
// the same involution -> 2-way (free) bank aliasing.
// Pipeline: 3 half-tiles in flight across each tile boundary, vmcnt(6)
// counted wait once per K-tile (vmcnt(0) only in the 2-tile tail).
// Race-freedom for staging t+2 into the live buffer: A frags are fully
// register-resident after phase 0; B half0 dead after phase 1 -> issue
// points (p1/p2/p3) are >=2 barriers after the last read of each region.
// ---------------------------------------------------------------------------
__global__ __launch_bounds__(512, 2) void lstm_layer_kernel(
    const __hip_bfloat16* __restrict__ A, const __hip_bfloat16* __restrict__ Wt,
    const float* __restrict__ bias, const float* __restrict__ c_in,
    float* __restrict__ out_h, float* __restrict__ out_c,
    float* __restrict__ out_final, __hip_bfloat16* __restrict__ xh_next) {
  // [0,32768): A dbuf (2 x 256x64)   [32768,65536): B dbuf (2 x 256x64)
  __shared__ __attribute__((aligned(16))) __hip_bfloat16 sm[4 * 256 * 64];

  const int tid = threadIdx.x;
  const int lane = tid & 63;
  const int wave = tid >> 6;  // 0..7
  const int wm = wave >> 2;   // 0..1  M half
  const int wn = wave & 3;    // 0..3  j slice
  const int m0 = blockIdx.y * 256;
  const int j0 = blockIdx.x * 64;

  // ---- staging constants: slot s = tid (+512); row r = s>>3, phys p = s&7,
  // source chunk q = p ^ (r&7) (involution; r&7 identical for both slots) ----
  const int r0 = tid >> 3;  // 0..63
  const int p = tid & 7;
  const int q = p ^ (r0 & 7);
  const __hip_bfloat16* aSrc[2][2];
  const __hip_bfloat16* bSrc[2][2];
#pragma unroll
  for (int h = 0; h < 2; h++)
#pragma unroll
    for (int i = 0; i < 2; i++) {
      const int r = r0 + i * 64;        // row within half 0..127
      const int ar = m0 + h * 128 + r;  // A row
      aSrc[h][i] = A + (size_t)ar * Kd + q * 8;
      const int tr = h * 128 + r;  // B tile row
      const int nrow = (tr >> 6) * Hh + j0 + (tr & 63);
      bSrc[h][i] = Wt + (size_t)nrow * Kd + q * 8;
    }

#define STAGEA(h, kt, buf)                                                  \
  do {                                                                      \
    __hip_bfloat16* _d = sm + (buf) * 16384 + (h) * 8192 + tid * 8;         \
    gload_lds16(aSrc[h][0] + (kt) * 64, _d);                                \
    gload_lds16(aSrc[h][1] + (kt) * 64, _d + 4096);                         \
  } while (0)
#define STAGEB(h, kt, buf)                                                  \
  do {                                                                      \
    __hip_bfloat16* _d = sm + 32768 + (buf) * 16384 + (h) * 8192 + tid * 8; \
    gload_lds16(bSrc[h][0] + (kt) * 64, _d);                                \
    gload_lds16(bSrc[h][1] + (kt) * 64, _d + 4096);                         \
  } while (0)

  // ---- read-side constants: R&7 == lane&7 (strides are mult of 8) ----
  const int qk = lane >> 4;  // k-chunk quarter
  const int lm = lane & 15;
  const int pc0 = qk ^ (lm & 7);        // phys chunk, k-step 0
  const int pc1 = (4 + qk) ^ (lm & 7);  // phys chunk, k-step 1
  const int aBase = (wm * 128 + lm) * 64;
  const int bBase = (wn * 16 + lm) * 64;

  floatx4 acc[8][4];  // [m-frag][gate]
#pragma unroll
  for (int mi = 0; mi < 8; mi++)
#pragma unroll
    for (int g = 0; g < 4; g++) acc[mi][g] = floatx4{0.f, 0.f, 0.f, 0.f};

  // ---- prologue: tile0 full + tile1 {A0,A1,B0}; keep 6 in flight ----
  STAGEA(0, 0, 0);
  STAGEA(1, 0, 0);
  STAGEB(0, 0, 0);
  STAGEB(1, 0, 0);
  STAGEA(0, 1, 1);
  STAGEA(1, 1, 1);
  STAGEB(0, 1, 1);
  asm volatile("s_waitcnt vmcnt(6)" ::: "memory");
  __builtin_amdgcn_sched_barrier(0);
  __builtin_amdgcn_s_barrier();

  for (int t = 0; t < NT; ++t) {
    const int cur = t & 1;
    const __hip_bfloat16* As_c = sm + cur * 16384;
    const __hip_bfloat16* Bs_c = sm + 32768 + cur * 16384;

    short8 af[8][2];
    short8 bfg[2];

    // ---- phase 0: read ALL A frags + B gate0; stage (t+1) B half1 ----
#pragma unroll
    for (int mi = 0; mi < 8; mi++) {
      af[mi][0] = *(const short8*)&As_c[aBase + mi * 1024 + pc0 * 8];
      af[mi][1] = *(const short8*)&As_c[aBase + mi * 1024 + pc1 * 8];
    }
    bfg[0] = *(const short8*)&Bs_c[bBase + pc0 * 8];
    bfg[1] = *(const short8*)&Bs_c[bBase + pc1 * 8];
    if (t + 1 < NT) STAGEB(1, t + 1, cur ^ 1);
    __builtin_amdgcn_s_barrier();
    asm volatile("s_waitcnt lgkmcnt(0)" ::: "memory");
    __builtin_amdgcn_sched_barrier(0);
    __builtin_amdgcn_s_setprio(1);
#pragma unroll
    for (int mi = 0; mi < 8; mi++) {
      acc[mi][0] = __builtin_amdgcn_mfma_f32_16x16x32_bf16(af[mi][0], bfg[0],
                                                           acc[mi][0], 0, 0, 0);
      acc[mi][0] = __builtin_amdgcn_mfma_f32_16x16x32_bf16(af[mi][1], bfg[1],
                                                           acc[mi][0], 0, 0, 0);
    }
    __builtin_amdgcn_s_setprio(0);
    __builtin_amdgcn_s_barrier();

    // ---- phases 1..3: read B gate g; stage (t+2) {A0,A1,B0} ----
#pragma unroll
    for (int g = 1; g < 4; g++) {
      bfg[0] = *(const short8*)&Bs_c[bBase + g * 4096 + pc0 * 8];
      bfg[1] = *(const short8*)&Bs_c[bBase + g * 4096 + pc1 * 8];
      if (t + 2 < NT) {
        if (g == 1)
          STAGEA(0, t + 2, cur);
        else if (g == 2)
          STAGEA(1, t + 2, cur);
        else
          STAGEB(0, t + 2, cur);
      }
      __builtin_amdgcn_s_barrier();
      asm volatile("s_waitcnt lgkmcnt(0)" ::: "memory");
      __builtin_amdgcn_sched_barrier(0);
      __builtin_amdgcn_s_setprio(1);
#pragma unroll
      for (int mi = 0; mi < 8; mi++) {
        acc[mi][g] = __builtin_amdgcn_mfma_f32_16x16x32_bf16(
            af[mi][0], bfg[0], acc[mi][g], 0, 0, 0);
        acc[mi][g] = __builtin_amdgcn_mfma_f32_16x16x32_bf16(
            af[mi][1], bfg[1], acc[mi][g], 0, 0, 0);
      }
      __builtin_amdgcn_s_setprio(0);
      if (g < 3) {
        __builtin_amdgcn_s_barrier();
      } else {
        // once per K-tile: drain tile t+1 fully, keep t+2's 3 halves in flight
        if (t < NT - 2)
          asm volatile("s_waitcnt vmcnt(6)" ::: "memory");
        else
          asm volatile("s_waitcnt vmcnt(0)" ::: "memory");
        __builtin_amdgcn_sched_barrier(0);
        __builtin_amdgcn_s_barrier();
      }
    }
  }

  // ---- epilogue: per-lane LSTM cell. C/D: col=lane&15, row=(lane>>4)*4+r ----
  const int j = j0 + wn * 16 + lm;  // gate column 0..1023
  const float bi = bias[j];
  const float bf_ = bias[Hh + j];
  const float bo = bias[2 * Hh + j];
  const float bg = bias[3 * Hh + j];
#pragma unroll
  for (int mi = 0; mi < 8; mi++) {
    const int row0 = m0 + wm * 128 + mi * 16 + qk * 4;
#pragma unroll
    for (int r = 0; r < 4; r++) {
      const int row = row0 + r;
      const float zi = acc[mi][0][r] + bi;
      const float zf = acc[mi][1][r] + bf_;
      const float zo = acc[mi][2][r] + bo;
      const float zg = acc[mi][3][r] + bg;
      const float ig = fast_sigmoid(zi);
      const float fg = fast_sigmoid(zf);
      const float og = fast_sigmoid(zo);
      const float gg = fast_tanh(zg);
      const float c = c_in[(size_t)row * Hh + j];
      const float cn = fmaf(c, fg, gg * ig);
      const float hn = fast_tanh(cn) * og;
      out_h[(size_t)row * Hh + j] = hn;
      out_c[(size_t)row * Hh + j] = cn;
      if (xh_next) xh_next[(size_t)row * Kd + j] = __float2bfloat16(hn);
      if (out_final) out_final[(size_t)row * Hh + j] = hn;
    }
  }
#undef STAGEA
#undef STAGEB
}

// ---------------------------------------------------------------------------
extern "C" void kernel_launch(void* const* d_in, const int* in_sizes, int n_in,
                              void* d_out, int out_size, void* d_ws,
                              size_t ws_size, hipStream_t stream) {
  const float* x = (const float*)d_in[0];     // [Bb][Ee]
  const float* s_h = (const float*)d_in[1];   // [DEPTH][Bb][Hh]
  const float* s_c = (const float*)d_in[2];   // [DEPTH][Bb][Hh]
  const float* W = (const float*)d_in[3];     // [DEPTH][Kd][Ng]
  const float* bias = (const float*)d_in[4];  // [DEPTH][Ng]
  float* out = (float*)d_out;

  // Workspace layout: Wt (64 MiB) | xh (64 MiB)  -> needs 128 MiB
  __hip_bfloat16* Wt = (__hip_bfloat16*)d_ws;
  __hip_bfloat16* xh =
      (__hip_bfloat16*)((char*)d_ws + (size_t)DEPTH * Ng * Kd * 2);

  transpose_w_kernel<<<dim3(Kd / 128, Ng / 64, DEPTH), 256, 0, stream>>>(W, Wt);
  prefill_xh_kernel<<<(Bb * Ee / 4 + DEPTH * Bb * Hh / 4) / 256, 256, 0,
                      stream>>>(x, s_h, xh);

  float* out_h = out + (size_t)Bb * Ee;            // h stack section
  float* out_c = out_h + (size_t)DEPTH * Bb * Hh;  // c stack section
  for (int l = 0; l < DEPTH; l++) {
    lstm_layer_kernel<<<dim3(Hh / 64, Bb / 256), 512, 0, stream>>>(
        xh + (size_t)l * Bb * Kd, Wt + (size_t)l * Ng * Kd,
        bias + (size_t)l * Ng, s_c + (size_t)l * Bb * Hh,
        out_h + (size_t)l * Bb * Hh, out_c + (size_t)l * Bb * Hh,
        (l == DEPTH - 1) ? out : nullptr,
        (l < DEPTH - 1) ? xh + (size_t)(l + 1) * Bb * Kd : nullptr);
  }
}

// Round 2
// 654.077 us; speedup vs baseline: 1.1541x; 1.0100x over previous
//
#include <hip/hip_runtime.h>
#include <hip/hip_bf16.h>
#include <stdint.h>

// Problem constants (from reference): DEPTH=4, B=4096, H=E=1024
#define DEPTH 4
#define Bb 4096
#define Hh 1024
#define Ee 1024
#define Kd 2048       // E + H
#define Ng 4096       // 4*H
#define NT (Kd / 64)  // 32 K-tiles of BK=64

typedef __attribute__((ext_vector_type(8))) short short8;   // 8 bf16 = 4 VGPRs
typedef __attribute__((ext_vector_type(4))) float floatx4;  // MFMA C/D frag
typedef __attribute__((ext_vector_type(4))) float f32x4;

__device__ __forceinline__ float fast_sigmoid(float x) {
  return 1.0f / (1.0f + __expf(-x));
}
__device__ __forceinline__ float fast_tanh(float x) {
  float t = __expf(-2.0f * fabsf(x));
  return copysignf((1.0f - t) / (1.0f + t), x);
}

// async global->LDS, 16B per lane; LDS dest = wave-uniform base + lane*16
__device__ __forceinline__ void gload_lds16(const void* g, void* l) {
  __builtin_amdgcn_global_load_lds(
      (const __attribute__((address_space(1))) void*)(uintptr_t)g,
      (__attribute__((address_space(3))) void*)(uint32_t)(uintptr_t)l,
      16, 0, 0);
}

// ---------------------------------------------------------------------------
// W[l][k][n] (f32) -> Wt[l][n][k] (bf16). Tile 128(k) x 64(n), block 256.
// (unchanged; will revisit once it surfaces in top-5)
// ---------------------------------------------------------------------------
__global__ __launch_bounds__(256) void transpose_w_kernel(
    const float* __restrict__ W, __hip_bfloat16* __restrict__ Wt) {
  __shared__ __attribute__((aligned(16))) float ldsT[64 * 132];  // 33 KB
  const int l = blockIdx.z;
  const int k0 = blockIdx.x * 128;
  const int n0 = blockIdx.y * 64;
  const float* Wl = W + (size_t)l * Kd * Ng + (size_t)k0 * Ng + n0;
  __hip_bfloat16* Wtl = Wt + (size_t)l * Ng * Kd;
  const int tid = threadIdx.x;

#pragma unroll
  for (int i = 0; i < 8; i++) {
    const int flat = tid + 256 * i;
    const int k = flat >> 4;         // 0..127
    const int c4 = (flat & 15) * 4;  // n offset 0..60
    const f32x4 v = *(const f32x4*)(Wl + (size_t)k * Ng + c4);
    const int grp = k >> 3;  // 8-f32 (32B) group along k
    const int klo = k & 7;
#pragma unroll
    for (int j = 0; j < 4; j++) {
      const int n = c4 + j;
      ldsT[n * 132 + ((grp ^ ((n >> 2) & 3)) << 3) + klo] = v[j];
    }
  }
  __syncthreads();

#pragma unroll
  for (int i = 0; i < 4; i++) {
    const int c = tid + 256 * i;
    const int n = c >> 4;   // 0..63
    const int kc = c & 15;  // 16B output chunk = 8 k
    const int g = kc ^ ((n >> 2) & 3);
    const float* src = &ldsT[n * 132 + (g << 3)];
    const f32x4 u0 = *(const f32x4*)src;
    const f32x4 u1 = *(const f32x4*)(src + 4);
    union {
      __hip_bfloat16 h[8];
      short8 s;
    } p;
    p.h[0] = __float2bfloat16(u0.x);
    p.h[1] = __float2bfloat16(u0.y);
    p.h[2] = __float2bfloat16(u0.z);
    p.h[3] = __float2bfloat16(u0.w);
    p.h[4] = __float2bfloat16(u1.x);
    p.h[5] = __float2bfloat16(u1.y);
    p.h[6] = __float2bfloat16(u1.z);
    p.h[7] = __float2bfloat16(u1.w);
    *(short8*)&Wtl[(size_t)(n0 + n) * Kd + k0 + kc * 8] = p.s;
  }
}

// ---------------------------------------------------------------------------
// xh[l] = [bf16(layer_input) | bf16(s_h[l])], layout [DEPTH][Bb][Kd] bf16.
// ---------------------------------------------------------------------------
__global__ __launch_bounds__(256) void prefill_xh_kernel(
    const float* __restrict__ x, const float* __restrict__ s_h,
    __hip_bfloat16* __restrict__ xh) {
  const int idx = blockIdx.x * blockDim.x + threadIdx.x;  // float4 index
  const int XN = Bb * Ee / 4;                             // 2^20
  const int TOTAL = XN + DEPTH * Bb * Hh / 4;
  if (idx >= TOTAL) return;
  const float* srcp;
  __hip_bfloat16* dst;
  if (idx < XN) {
    const int b = idx >> 8;  // Ee/4 = 256
    const int j4 = idx & 255;
    srcp = x + (size_t)idx * 4;
    dst = xh + (size_t)b * Kd + j4 * 4;
  } else {
    const int e4 = idx - XN;
    const int l = e4 >> 20;  // Bb*Hh/4 = 2^20
    const int r = e4 & 0xFFFFF;
    const int b = r >> 8;  // Hh/4 = 256
    const int j4 = r & 255;
    srcp = s_h + (size_t)e4 * 4;
    dst = xh + (size_t)l * Bb * Kd + (size_t)b * Kd + Ee + j4 * 4;
  }
  f32x4 v = *(const f32x4*)srcp;
  union {
    __hip_bfloat16 h[4];
    unsigned long long u;
  } p;
  p.h[0] = __float2bfloat16(v.x);
  p.h[1] = __float2bfloat16(v.y);
  p.h[2] = __float2bfloat16(v.z);
  p.h[3] = __float2bfloat16(v.w);
  *(unsigned long long*)dst = p.u;
}

// ---------------------------------------------------------------------------
// Fused GEMM + LSTM cell, 256^2 tile, 2-barrier/K-tile counted-wait schedule.
// A = xh[l] [Bb][Kd] bf16;  Wt [Ng][Kd] bf16 (row n = gate*1024 + j)
// 512 thr = 8 waves (2M x 4N); wave output 128x64; N-frag index == gate.
// Per K-tile: issue ALL 24 ds_read_b128 at top (ordered to match use; the
// compiler's fine-grained per-operand lgkmcnt makes reads deliver under the
// MFMAs) -> Q00+Q10 (32 MFMA) -> lgkmcnt(0)+barrier (ALL cur reads drained
// before anyone stages t+2 into cur) -> stage {A0,A1,B0}(t+2) -> Q01+Q11
// (32 MFMA, cover staging + counted vmcnt) -> vmcnt(6)+barrier.
// vmcnt FIFO: outstanding at tile end = {A0A1B0(t+1) [t-1 mid], B1(t+1)
// [t top], A0A1B0(t+2) [t mid]} = 14; wait 6 drains exactly tile t+1's 8.
// Hazards: B1(t+1) write is 2 barriers after its last reader (t-1's gates
// 2,3 reads drained by t-1's lgkmcnt(0)); A/B-half0(t+2) staging is 1
// barrier after per-wave lgkmcnt(0); B-half1 is never staged mid-tile, so
// late bfg reads can't race staging.
// ---------------------------------------------------------------------------
__global__ __launch_bounds__(512, 2) void lstm_layer_kernel(
    const __hip_bfloat16* __restrict__ A, const __hip_bfloat16* __restrict__ Wt,
    const float* __restrict__ bias, const float* __restrict__ c_in,
    float* __restrict__ out_h, float* __restrict__ out_c,
    float* __restrict__ out_final, __hip_bfloat16* __restrict__ xh_next) {
  // [0,32768): A dbuf (2 x 256x64)   [32768,65536): B dbuf (2 x 256x64)
  __shared__ __attribute__((aligned(16))) __hip_bfloat16 sm[4 * 256 * 64];

  const int tid = threadIdx.x;
  const int lane = tid & 63;
  const int wave = tid >> 6;  // 0..7
  const int wm = wave >> 2;   // 0..1  M half
  const int wn = wave & 3;    // 0..3  j slice
  const int m0 = blockIdx.y * 256;
  const int j0 = blockIdx.x * 64;

  // ---- staging: slot tid covers rows r0, r0+64 of each half; phys chunk p
  // holds source chunk q = p ^ (r&7) (involution, same for r0 and r0+64) ----
  const int r0 = tid >> 3;  // 0..63
  const int p = tid & 7;
  const int q = p ^ (r0 & 7);
  // single base pointers; per-STAGE offsets are compile-time multiples of Kd
  const __hip_bfloat16* aS = A + (size_t)(m0 + r0) * Kd + q * 8;
  const __hip_bfloat16* bS = Wt + (size_t)(j0 + r0) * Kd + q * 8;

#define STAGEA(h, kt, buf)                                          \
  do {                                                              \
    __hip_bfloat16* _d = sm + (buf) * 16384 + (h) * 8192 + tid * 8; \
    gload_lds16(aS + (size_t)((h) * 128) * Kd + (kt) * 64, _d);     \
    gload_lds16(aS + (size_t)((h) * 128 + 64) * Kd + (kt) * 64,     \
                _d + 4096);                                         \
  } while (0)
#define STAGEB(h, kt, buf)                                                  \
  do {                                                                      \
    __hip_bfloat16* _d = sm + 32768 + (buf) * 16384 + (h) * 8192 + tid * 8; \
    gload_lds16(bS + (size_t)((h) * 2) * 1024 * Kd + (kt) * 64, _d);        \
    gload_lds16(bS + (size_t)((h) * 2 + 1) * 1024 * Kd + (kt) * 64,         \
                _d + 4096);                                                 \
  } while (0)

  // ---- read-side constants: R&7 == lane&7 (row strides are mult of 8) ----
  const int qk = lane >> 4;  // k-chunk quarter
  const int lm = lane & 15;
  const int pc0 = qk ^ (lm & 7);        // phys chunk, k-step 0
  const int pc1 = (4 + qk) ^ (lm & 7);  // phys chunk, k-step 1
  const int aBase = (wm * 128 + lm) * 64;
  const int bBase = (wn * 16 + lm) * 64;

  floatx4 acc[8][4];  // [m-frag][gate]
#pragma unroll
  for (int mi = 0; mi < 8; mi++)
#pragma unroll
    for (int g = 0; g < 4; g++) acc[mi][g] = floatx4{0.f, 0.f, 0.f, 0.f};

  // ---- prologue: tile0 full + tile1 {A0,A1,B0}; 6 stay in flight ----
  STAGEA(0, 0, 0);
  STAGEA(1, 0, 0);
  STAGEB(0, 0, 0);
  STAGEB(1, 0, 0);
  STAGEA(0, 1, 1);
  STAGEA(1, 1, 1);
  STAGEB(0, 1, 1);
  asm volatile("s_waitcnt vmcnt(6)" ::: "memory");
  __builtin_amdgcn_sched_barrier(0);
  __builtin_amdgcn_s_barrier();

  for (int t = 0; t < NT; ++t) {
    const int cur = t & 1;
    const __hip_bfloat16* As_c = sm + cur * 16384;
    const __hip_bfloat16* Bs_c = sm + 32768 + cur * 16384;

    short8 af[8][2];
    short8 bfg[4][2];

    // ---- issue all 24 reads, Q00's operand set first ----
#pragma unroll
    for (int mi = 0; mi < 4; mi++) {
      af[mi][0] = *(const short8*)&As_c[aBase + mi * 1024 + pc0 * 8];
      af[mi][1] = *(const short8*)&As_c[aBase + mi * 1024 + pc1 * 8];
    }
#pragma unroll
    for (int g = 0; g < 2; g++) {
      bfg[g][0] = *(const short8*)&Bs_c[bBase + g * 4096 + pc0 * 8];
      bfg[g][1] = *(const short8*)&Bs_c[bBase + g * 4096 + pc1 * 8];
    }
    if (t + 1 < NT) STAGEB(1, t + 1, cur ^ 1);
#pragma unroll
    for (int mi = 4; mi < 8; mi++) {
      af[mi][0] = *(const short8*)&As_c[aBase + mi * 1024 + pc0 * 8];
      af[mi][1] = *(const short8*)&As_c[aBase + mi * 1024 + pc1 * 8];
    }
#pragma unroll
    for (int g = 2; g < 4; g++) {
      bfg[g][0] = *(const short8*)&Bs_c[bBase + g * 4096 + pc0 * 8];
      bfg[g][1] = *(const short8*)&Bs_c[bBase + g * 4096 + pc1 * 8];
    }

    // ---- first half: Q00 (mi0-3 x g0-1) + Q10 (mi4-7 x g0-1) ----
    __builtin_amdgcn_s_setprio(1);
#pragma unroll
    for (int mi = 0; mi < 8; mi++)
#pragma unroll
      for (int g = 0; g < 2; g++) {
        acc[mi][g] = __builtin_amdgcn_mfma_f32_16x16x32_bf16(
            af[mi][0], bfg[g][0], acc[mi][g], 0, 0, 0);
        acc[mi][g] = __builtin_amdgcn_mfma_f32_16x16x32_bf16(
            af[mi][1], bfg[g][1], acc[mi][g], 0, 0, 0);
      }
    __builtin_amdgcn_s_setprio(0);

    // ---- safety anchor: every wave drains ALL cur reads, then barrier ----
    asm volatile("s_waitcnt lgkmcnt(0)" ::: "memory");
    __builtin_amdgcn_sched_barrier(0);
    __builtin_amdgcn_s_barrier();

    // ---- stage t+2 into cur (A halves + B half0; B half1 next tile top) ---
    if (t + 2 < NT) {
      STAGEA(0, t + 2, cur);
      STAGEA(1, t + 2, cur);
      STAGEB(0, t + 2, cur);
    }

    // ---- second half: Q01 (mi0-3 x g2-3) + Q11 (mi4-7 x g2-3) ----
    __builtin_amdgcn_s_setprio(1);
#pragma unroll
    for (int mi = 0; mi < 8; mi++)
#pragma unroll
      for (int g = 2; g < 4; g++) {
        acc[mi][g] = __builtin_amdgcn_mfma_f32_16x16x32_bf16(
            af[mi][0], bfg[g][0], acc[mi][g], 0, 0, 0);
        acc[mi][g] = __builtin_amdgcn_mfma_f32_16x16x32_bf16(
            af[mi][1], bfg[g][1], acc[mi][g], 0, 0, 0);
      }
    __builtin_amdgcn_s_setprio(0);

    // ---- once per K-tile: drain exactly tile t+1's 8 loads ----
    if (t < NT - 2)
      asm volatile("s_waitcnt vmcnt(6)" ::: "memory");
    else
      asm volatile("s_waitcnt vmcnt(0)" ::: "memory");
    __builtin_amdgcn_sched_barrier(0);
    __builtin_amdgcn_s_barrier();
  }

  // ---- epilogue: per-lane LSTM cell. C/D: col=lane&15, row=(lane>>4)*4+r ---
  const int j = j0 + wn * 16 + lm;  // gate column 0..1023
  const float bi = bias[j];
  const float bf_ = bias[Hh + j];
  const float bo = bias[2 * Hh + j];
  const float bg = bias[3 * Hh + j];
#pragma unroll
  for (int mi = 0; mi < 8; mi++) {
    const int row0 = m0 + wm * 128 + mi * 16 + qk * 4;
#pragma unroll
    for (int r = 0; r < 4; r++) {
      const int row = row0 + r;
      const float zi = acc[mi][0][r] + bi;
      const float zf = acc[mi][1][r] + bf_;
      const float zo = acc[mi][2][r] + bo;
      const float zg = acc[mi][3][r] + bg;
      const float ig = fast_sigmoid(zi);
      const float fg = fast_sigmoid(zf);
      const float og = fast_sigmoid(zo);
      const float gg = fast_tanh(zg);
      const float c = c_in[(size_t)row * Hh + j];
      const float cn = fmaf(c, fg, gg * ig);
      const float hn = fast_tanh(cn) * og;
      out_h[(size_t)row * Hh + j] = hn;
      out_c[(size_t)row * Hh + j] = cn;
      if (xh_next) xh_next[(size_t)row * Kd + j] = __float2bfloat16(hn);
      if (out_final) out_final[(size_t)row * Hh + j] = hn;
    }
  }
#undef STAGEA
#undef STAGEB
}

// ---------------------------------------------------------------------------
extern "C" void kernel_launch(void* const* d_in, const int* in_sizes, int n_in,
                              void* d_out, int out_size, void* d_ws,
                              size_t ws_size, hipStream_t stream) {
  const float* x = (const float*)d_in[0];     // [Bb][Ee]
  const float* s_h = (const float*)d_in[1];   // [DEPTH][Bb][Hh]
  const float* s_c = (const float*)d_in[2];   // [DEPTH][Bb][Hh]
  const float* W = (const float*)d_in[3];     // [DEPTH][Kd][Ng]
  const float* bias = (const float*)d_in[4];  // [DEPTH][Ng]
  float* out = (float*)d_out;

  // Workspace layout: Wt (64 MiB) | xh (64 MiB)  -> needs 128 MiB
  __hip_bfloat16* Wt = (__hip_bfloat16*)d_ws;
  __hip_bfloat16* xh =
      (__hip_bfloat16*)((char*)d_ws + (size_t)DEPTH * Ng * Kd * 2);

  transpose_w_kernel<<<dim3(Kd / 128, Ng / 64, DEPTH), 256, 0, stream>>>(W, Wt);
  prefill_xh_kernel<<<(Bb * Ee / 4 + DEPTH * Bb * Hh / 4) / 256, 256, 0,
                      stream>>>(x, s_h, xh);

  float* out_h = out + (size_t)Bb * Ee;            // h stack section
  float* out_c = out_h + (size_t)DEPTH * Bb * Hh;  // c stack section
  for (int l = 0; l < DEPTH; l++) {
    lstm_layer_kernel<<<dim3(Hh / 64, Bb / 256), 512, 0, stream>>>(
        xh + (size_t)l * Bb * Kd, Wt + (size_t)l * Ng * Kd,
        bias + (size_t)l * Ng, s_c + (size_t)l * Bb * Hh,
        out_h + (size_t)l * Bb * Hh, out_c + (size_t)l * Bb * Hh,
        (l == DEPTH - 1) ? out : nullptr,
        (l < DEPTH - 1) ? xh + (size_t)(l + 1) * Bb * Kd : nullptr);
  }
}

// Round 3
// 653.610 us; speedup vs baseline: 1.1549x; 1.0007x over previous
//
#include <hip/hip_runtime.h>
#include <hip/hip_bf16.h>
#include <stdint.h>

// Problem constants (from reference): DEPTH=4, B=4096, H=E=1024
#define DEPTH 4
#define Bb 4096
#define Hh 1024
#define Ee 1024
#define Kd 2048       // E + H
#define Ng 4096       // 4*H
#define NT (Kd / 64)  // 32 K-tiles of BK=64

typedef __attribute__((ext_vector_type(8))) short short8;   // 8 bf16 = 4 VGPRs
typedef __attribute__((ext_vector_type(4))) float floatx4;  // MFMA C/D frag
typedef __attribute__((ext_vector_type(4))) float f32x4;

__device__ __forceinline__ float fast_sigmoid(float x) {
  return 1.0f / (1.0f + __expf(-x));
}
__device__ __forceinline__ float fast_tanh(float x) {
  float t = __expf(-2.0f * fabsf(x));
  return copysignf((1.0f - t) / (1.0f + t), x);
}

// async global->LDS, 16B per lane; LDS dest = wave-uniform base + lane*16
__device__ __forceinline__ void gload_lds16(const void* g, void* l) {
  __builtin_amdgcn_global_load_lds(
      (const __attribute__((address_space(1))) void*)(uintptr_t)g,
      (__attribute__((address_space(3))) void*)(uint32_t)(uintptr_t)l,
      16, 0, 0);
}

// ---------------------------------------------------------------------------
// W[l][k][n] (f32) -> Wt[l][n][k] (bf16). Tile 128(k) x 64(n), block 256.
// (unchanged; revisit once it surfaces in top-5)
// ---------------------------------------------------------------------------
__global__ __launch_bounds__(256) void transpose_w_kernel(
    const float* __restrict__ W, __hip_bfloat16* __restrict__ Wt) {
  __shared__ __attribute__((aligned(16))) float ldsT[64 * 132];  // 33 KB
  const int l = blockIdx.z;
  const int k0 = blockIdx.x * 128;
  const int n0 = blockIdx.y * 64;
  const float* Wl = W + (size_t)l * Kd * Ng + (size_t)k0 * Ng + n0;
  __hip_bfloat16* Wtl = Wt + (size_t)l * Ng * Kd;
  const int tid = threadIdx.x;

#pragma unroll
  for (int i = 0; i < 8; i++) {
    const int flat = tid + 256 * i;
    const int k = flat >> 4;         // 0..127
    const int c4 = (flat & 15) * 4;  // n offset 0..60
    const f32x4 v = *(const f32x4*)(Wl + (size_t)k * Ng + c4);
    const int grp = k >> 3;  // 8-f32 (32B) group along k
    const int klo = k & 7;
#pragma unroll
    for (int j = 0; j < 4; j++) {
      const int n = c4 + j;
      ldsT[n * 132 + ((grp ^ ((n >> 2) & 3)) << 3) + klo] = v[j];
    }
  }
  __syncthreads();

#pragma unroll
  for (int i = 0; i < 4; i++) {
    const int c = tid + 256 * i;
    const int n = c >> 4;   // 0..63
    const int kc = c & 15;  // 16B output chunk = 8 k
    const int g = kc ^ ((n >> 2) & 3);
    const float* src = &ldsT[n * 132 + (g << 3)];
    const f32x4 u0 = *(const f32x4*)src;
    const f32x4 u1 = *(const f32x4*)(src + 4);
    union {
      __hip_bfloat16 h[8];
      short8 s;
    } p;
    p.h[0] = __float2bfloat16(u0.x);
    p.h[1] = __float2bfloat16(u0.y);
    p.h[2] = __float2bfloat16(u0.z);
    p.h[3] = __float2bfloat16(u0.w);
    p.h[4] = __float2bfloat16(u1.x);
    p.h[5] = __float2bfloat16(u1.y);
    p.h[6] = __float2bfloat16(u1.z);
    p.h[7] = __float2bfloat16(u1.w);
    *(short8*)&Wtl[(size_t)(n0 + n) * Kd + k0 + kc * 8] = p.s;
  }
}

// ---------------------------------------------------------------------------
// xh[l] = [bf16(layer_input) | bf16(s_h[l])], layout [DEPTH][Bb][Kd] bf16.
// ---------------------------------------------------------------------------
__global__ __launch_bounds__(256) void prefill_xh_kernel(
    const float* __restrict__ x, const float* __restrict__ s_h,
    __hip_bfloat16* __restrict__ xh) {
  const int idx = blockIdx.x * blockDim.x + threadIdx.x;  // float4 index
  const int XN = Bb * Ee / 4;                             // 2^20
  const int TOTAL = XN + DEPTH * Bb * Hh / 4;
  if (idx >= TOTAL) return;
  const float* srcp;
  __hip_bfloat16* dst;
  if (idx < XN) {
    const int b = idx >> 8;  // Ee/4 = 256
    const int j4 = idx & 255;
    srcp = x + (size_t)idx * 4;
    dst = xh + (size_t)b * Kd + j4 * 4;
  } else {
    const int e4 = idx - XN;
    const int l = e4 >> 20;  // Bb*Hh/4 = 2^20
    const int r = e4 & 0xFFFFF;
    const int b = r >> 8;  // Hh/4 = 256
    const int j4 = r & 255;
    srcp = s_h + (size_t)e4 * 4;
    dst = xh + (size_t)l * Bb * Kd + (size_t)b * Kd + Ee + j4 * 4;
  }
  f32x4 v = *(const f32x4*)srcp;
  union {
    __hip_bfloat16 h[4];
    unsigned long long u;
  } p;
  p.h[0] = __float2bfloat16(v.x);
  p.h[1] = __float2bfloat16(v.y);
  p.h[2] = __float2bfloat16(v.z);
  p.h[3] = __float2bfloat16(v.w);
  *(unsigned long long*)dst = p.u;
}

// ---------------------------------------------------------------------------
// Fused GEMM + LSTM cell, 256^2 tile, software-pipelined quadrant schedule.
// A = xh[l] [Bb][Kd] bf16;  Wt [Ng][Kd] bf16 (row n = gate*1024 + j)
// 512 thr = 8 waves (2M x 4N); wave output 128x64; N-frag index == gate.
//
// Per K-tile t (1 barrier, counted lgkm waits; every read issued one
// MFMA-phase before use so delivery hides under the matrix pipe):
//  P0: issue b01(t)[4 ds]; lgkm(4) [af0,b23 done]; 16 MFMA af0 x b23
//  P1: issue af1(t)[8 ds]; lgkm(8) [b01 done];     16 MFMA af0 x b01
//  MID: lgkm(0) [all buf(t) reads done] + vmcnt(0) [t+1's 8 stages landed]
//       + barrier; then issue af0(t+1)[8 ds, dead regs] and stage t+2
//       (4 halves -> buf(t), whose reads all retired before the barrier)
//  P2: 16 MFMA af1 x b01  (resident; covers af0' delivery + gload issue)
//  P3: 16 MFMA af1 x b23; then issue b23(t+1)[4 ds, dead regs]
// lgkm FIFO at next P0: af0'(8)+b23'(4)+b01'(4) -> lgkm(4) drains af0'+b23'.
// Operand regs: af0 32 + af1 32 + b01 16 + b23 16 = 96 VGPR (+128 acc AGPR)
// -- at the 256/wave limit for 2 waves/SIMD, same as previous round.
// Swizzle: source chunk q = p ^ (r&7) staged at phys slot p (linear
// gload_lds dest), reads XOR the same involution (verified, 0 conflicts).
// ---------------------------------------------------------------------------
__global__ __launch_bounds__(512, 2) void lstm_layer_kernel(
    const __hip_bfloat16* __restrict__ A, const __hip_bfloat16* __restrict__ Wt,
    const float* __restrict__ bias, const float* __restrict__ c_in,
    float* __restrict__ out_h, float* __restrict__ out_c,
    float* __restrict__ out_final, __hip_bfloat16* __restrict__ xh_next) {
  // [0,32768): A dbuf (2 x 256x64)   [32768,65536): B dbuf (2 x 256x64)
  __shared__ __attribute__((aligned(16))) __hip_bfloat16 sm[4 * 256 * 64];

  const int tid = threadIdx.x;
  const int lane = tid & 63;
  const int wave = tid >> 6;  // 0..7
  const int wm = wave >> 2;   // 0..1  M half
  const int wn = wave & 3;    // 0..3  j slice
  const int m0 = blockIdx.y * 256;
  const int j0 = blockIdx.x * 64;

  // ---- staging: slot tid covers rows r0, r0+64 of each half; phys chunk p
  // holds source chunk q = p ^ (r&7) (involution, same for r0 and r0+64) ----
  const int r0 = tid >> 3;  // 0..63
  const int p = tid & 7;
  const int q = p ^ (r0 & 7);
  const __hip_bfloat16* aS = A + (size_t)(m0 + r0) * Kd + q * 8;
  const __hip_bfloat16* bS = Wt + (size_t)(j0 + r0) * Kd + q * 8;

#define STAGEA(h, kt, buf)                                          \
  do {                                                              \
    __hip_bfloat16* _d = sm + (buf) * 16384 + (h) * 8192 + tid * 8; \
    gload_lds16(aS + (size_t)((h) * 128) * Kd + (kt) * 64, _d);     \
    gload_lds16(aS + (size_t)((h) * 128 + 64) * Kd + (kt) * 64,     \
                _d + 4096);                                         \
  } while (0)
#define STAGEB(h, kt, buf)                                                  \
  do {                                                                      \
    __hip_bfloat16* _d = sm + 32768 + (buf) * 16384 + (h) * 8192 + tid * 8; \
    gload_lds16(bS + (size_t)((h) * 2) * 1024 * Kd + (kt) * 64, _d);        \
    gload_lds16(bS + (size_t)((h) * 2 + 1) * 1024 * Kd + (kt) * 64,         \
                _d + 4096);                                                 \
  } while (0)

  // ---- read-side constants: R&7 == lane&7 (row strides are mult of 8) ----
  const int qk = lane >> 4;  // k-chunk quarter
  const int lm = lane & 15;
  const int pc0 = qk ^ (lm & 7);        // phys chunk, k-step 0
  const int pc1 = (4 + qk) ^ (lm & 7);  // phys chunk, k-step 1
  const int aBase = (wm * 128 + lm) * 64;
  const int bBase = (wn * 16 + lm) * 64;

  floatx4 acc[8][4];  // [m-frag][gate]
#pragma unroll
  for (int mi = 0; mi < 8; mi++)
#pragma unroll
    for (int g = 0; g < 4; g++) acc[mi][g] = floatx4{0.f, 0.f, 0.f, 0.f};

  short8 af0[4][2];  // A frags mi 0..3
  short8 af1[4][2];  // A frags mi 4..7
  short8 b01[2][2];  // B gates 0,1
  short8 b23[2][2];  // B gates 2,3

#define QUAD16(MB, GB, AF, BF)                                              \
  do {                                                                      \
    _Pragma("unroll") for (int mi = 0; mi < 4; mi++) {                      \
      _Pragma("unroll") for (int g = 0; g < 2; g++) {                       \
        acc[(MB) + mi][(GB) + g] = __builtin_amdgcn_mfma_f32_16x16x32_bf16( \
            AF[mi][0], BF[g][0], acc[(MB) + mi][(GB) + g], 0, 0, 0);        \
        acc[(MB) + mi][(GB) + g] = __builtin_amdgcn_mfma_f32_16x16x32_bf16( \
            AF[mi][1], BF[g][1], acc[(MB) + mi][(GB) + g], 0, 0, 0);        \
      }                                                                     \
    }                                                                       \
  } while (0)

  // ---- prologue: stage tiles 0 and 1; pre-read af0+b23 of tile 0 ----
  STAGEA(0, 0, 0);
  STAGEA(1, 0, 0);
  STAGEB(0, 0, 0);
  STAGEB(1, 0, 0);
  STAGEA(0, 1, 1);
  STAGEA(1, 1, 1);
  STAGEB(0, 1, 1);
  STAGEB(1, 1, 1);
  asm volatile("s_waitcnt vmcnt(8)" ::: "memory");  // tile0's 8 landed
  __builtin_amdgcn_sched_barrier(0);
  __builtin_amdgcn_s_barrier();
  {
    const __hip_bfloat16* As0 = sm;
    const __hip_bfloat16* Bs0 = sm + 32768;
#pragma unroll
    for (int mi = 0; mi < 4; mi++) {
      af0[mi][0] = *(const short8*)&As0[aBase + mi * 1024 + pc0 * 8];
      af0[mi][1] = *(const short8*)&As0[aBase + mi * 1024 + pc1 * 8];
    }
#pragma unroll
    for (int g = 0; g < 2; g++) {
      b23[g][0] = *(const short8*)&Bs0[bBase + (g + 2) * 4096 + pc0 * 8];
      b23[g][1] = *(const short8*)&Bs0[bBase + (g + 2) * 4096 + pc1 * 8];
    }
  }

  for (int t = 0; t < NT; ++t) {
    const int cur = t & 1;
    const __hip_bfloat16* As_c = sm + cur * 16384;
    const __hip_bfloat16* Bs_c = sm + 32768 + cur * 16384;
    const __hip_bfloat16* As_n = sm + (cur ^ 1) * 16384;
    const __hip_bfloat16* Bs_n = sm + 32768 + (cur ^ 1) * 16384;

    // ---- P0: issue b01(t); wait af0+b23; MFMA af0 x b23 ----
#pragma unroll
    for (int g = 0; g < 2; g++) {
      b01[g][0] = *(const short8*)&Bs_c[bBase + g * 4096 + pc0 * 8];
      b01[g][1] = *(const short8*)&Bs_c[bBase + g * 4096 + pc1 * 8];
    }
    asm volatile("s_waitcnt lgkmcnt(4)" ::: "memory");
    __builtin_amdgcn_sched_barrier(0);
    __builtin_amdgcn_s_setprio(1);
    QUAD16(0, 2, af0, b23);
    __builtin_amdgcn_s_setprio(0);

    // ---- P1: issue af1(t); wait b01; MFMA af0 x b01 ----
#pragma unroll
    for (int mi = 0; mi < 4; mi++) {
      af1[mi][0] = *(const short8*)&As_c[aBase + (mi + 4) * 1024 + pc0 * 8];
      af1[mi][1] = *(const short8*)&As_c[aBase + (mi + 4) * 1024 + pc1 * 8];
    }
    asm volatile("s_waitcnt lgkmcnt(8)" ::: "memory");
    __builtin_amdgcn_sched_barrier(0);
    __builtin_amdgcn_s_setprio(1);
    QUAD16(0, 0, af0, b01);
    __builtin_amdgcn_s_setprio(0);

    // ---- MID: all buf(t) reads retired + t+1's stages landed; barrier ----
    asm volatile("s_waitcnt lgkmcnt(0)" ::: "memory");
    asm volatile("s_waitcnt vmcnt(0)" ::: "memory");
    __builtin_amdgcn_sched_barrier(0);
    __builtin_amdgcn_s_barrier();

    if (t + 1 < NT) {  // prefetch af0(t+1) into dead regs
#pragma unroll
      for (int mi = 0; mi < 4; mi++) {
        af0[mi][0] = *(const short8*)&As_n[aBase + mi * 1024 + pc0 * 8];
        af0[mi][1] = *(const short8*)&As_n[aBase + mi * 1024 + pc1 * 8];
      }
    }
    if (t + 2 < NT) {  // stage tile t+2 into buf(t) (reads retired above)
      STAGEA(0, t + 2, cur);
      STAGEA(1, t + 2, cur);
      STAGEB(0, t + 2, cur);
      STAGEB(1, t + 2, cur);
    }

    // ---- P2: MFMA af1 x b01 (resident; covers af0' + gload issue) ----
    __builtin_amdgcn_s_setprio(1);
    QUAD16(4, 0, af1, b01);
    __builtin_amdgcn_s_setprio(0);

    // ---- P3: MFMA af1 x b23; then prefetch b23(t+1) into dead regs ----
    __builtin_amdgcn_s_setprio(1);
    QUAD16(4, 2, af1, b23);
    __builtin_amdgcn_s_setprio(0);
    if (t + 1 < NT) {
#pragma unroll
      for (int g = 0; g < 2; g++) {
        b23[g][0] = *(const short8*)&Bs_n[bBase + (g + 2) * 4096 + pc0 * 8];
        b23[g][1] = *(const short8*)&Bs_n[bBase + (g + 2) * 4096 + pc1 * 8];
      }
    }
  }

  // ---- epilogue: per-lane LSTM cell. C/D: col=lane&15, row=(lane>>4)*4+r ---
  const int j = j0 + wn * 16 + lm;  // gate column 0..1023
  const float bi = bias[j];
  const float bf_ = bias[Hh + j];
  const float bo = bias[2 * Hh + j];
  const float bg = bias[3 * Hh + j];
#pragma unroll
  for (int mi = 0; mi < 8; mi++) {
    const int row0 = m0 + wm * 128 + mi * 16 + qk * 4;
#pragma unroll
    for (int r = 0; r < 4; r++) {
      const int row = row0 + r;
      const float zi = acc[mi][0][r] + bi;
      const float zf = acc[mi][1][r] + bf_;
      const float zo = acc[mi][2][r] + bo;
      const float zg = acc[mi][3][r] + bg;
      const float ig = fast_sigmoid(zi);
      const float fg = fast_sigmoid(zf);
      const float og = fast_sigmoid(zo);
      const float gg = fast_tanh(zg);
      const float c = c_in[(size_t)row * Hh + j];
      const float cn = fmaf(c, fg, gg * ig);
      const float hn = fast_tanh(cn) * og;
      out_h[(size_t)row * Hh + j] = hn;
      out_c[(size_t)row * Hh + j] = cn;
      if (xh_next) xh_next[(size_t)row * Kd + j] = __float2bfloat16(hn);
      if (out_final) out_final[(size_t)row * Hh + j] = hn;
    }
  }
#undef STAGEA
#undef STAGEB
#undef QUAD16
}

// ---------------------------------------------------------------------------
extern "C" void kernel_launch(void* const* d_in, const int* in_sizes, int n_in,
                              void* d_out, int out_size, void* d_ws,
                              size_t ws_size, hipStream_t stream) {
  const float* x = (const float*)d_in[0];     // [Bb][Ee]
  const float* s_h = (const float*)d_in[1];   // [DEPTH][Bb][Hh]
  const float* s_c = (const float*)d_in[2];   // [DEPTH][Bb][Hh]
  const float* W = (const float*)d_in[3];     // [DEPTH][Kd][Ng]
  const float* bias = (const float*)d_in[4];  // [DEPTH][Ng]
  float* out = (float*)d_out;

  // Workspace layout: Wt (64 MiB) | xh (64 MiB)  -> needs 128 MiB
  __hip_bfloat16* Wt = (__hip_bfloat16*)d_ws;
  __hip_bfloat16* xh =
      (__hip_bfloat16*)((char*)d_ws + (size_t)DEPTH * Ng * Kd * 2);

  transpose_w_kernel<<<dim3(Kd / 128, Ng / 64, DEPTH), 256, 0, stream>>>(W, Wt);
  prefill_xh_kernel<<<(Bb * Ee / 4 + DEPTH * Bb * Hh / 4) / 256, 256, 0,
                      stream>>>(x, s_h, xh);

  float* out_h = out + (size_t)Bb * Ee;            // h stack section
  float* out_c = out_h + (size_t)DEPTH * Bb * Hh;  // c stack section
  for (int l = 0; l < DEPTH; l++) {
    lstm_layer_kernel<<<dim3(Hh / 64, Bb / 256), 512, 0, stream>>>(
        xh + (size_t)l * Bb * Kd, Wt + (size_t)l * Ng * Kd,
        bias + (size_t)l * Ng, s_c + (size_t)l * Bb * Hh,
        out_h + (size_t)l * Bb * Hh, out_c + (size_t)l * Bb * Hh,
        (l == DEPTH - 1) ? out : nullptr,
        (l < DEPTH - 1) ? xh + (size_t)(l + 1) * Bb * Kd : nullptr);
  }
}